// Round 9
// baseline (536.354 us; speedup 1.0000x reference)
//
#include <hip/hip_runtime.h>

// SP_Attentation v6: all-fp16 1-term pipeline; attn = 2-wave blocks (grid 768),
// V register-prefetch across the single per-iter barrier (all waits counted),
// K double-buffered LDS via gll; proj = barrier-free wave-private, fixed
// last-iter vmcnt soundness.

typedef _Float16 f16x8 __attribute__((ext_vector_type(8)));
typedef _Float16 f16x4 __attribute__((ext_vector_type(4)));
typedef _Float16 f16x2 __attribute__((ext_vector_type(2)));
typedef float    f32x4 __attribute__((ext_vector_type(4)));
typedef unsigned int u32;

#define MFMA(a,b,c) __builtin_amdgcn_mfma_f32_16x16x32_f16((a),(b),(c),0,0,0)

typedef __attribute__((address_space(1))) const u32 gu32_t;
typedef __attribute__((address_space(3))) u32 lu32_t;

__device__ __forceinline__ void gll16(const void* g, void* l) {
  __builtin_amdgcn_global_load_lds((gu32_t*)g, (lu32_t*)l, 16, 0, 0);
}
#define VMCNT(n)  asm volatile("s_waitcnt vmcnt(" #n ")" ::: "memory")
#define LGKMCNT0() asm volatile("s_waitcnt lgkmcnt(0)" ::: "memory")
#define BAR() __builtin_amdgcn_s_barrier()

__constant__ int c_off[9] = {0, 3072, 7168, 9216, 12800, 15360, 19456, 22528, 24576};

static constexpr int NTOK = 24576;
static constexpr int C    = 256;

// ---------------- kernel A0: W fp32 -> fp16 ----------------
__global__ __launch_bounds__(256) void wsplit_kernel(
    const float* __restrict__ Wq, const float* __restrict__ Wk, const float* __restrict__ Wv,
    _Float16* __restrict__ Whi)
{
  int idx = blockIdx.x * 256 + threadIdx.x;  // 3*65536 total
  int mat = idx >> 16;
  int r   = idx & 65535;
  const float* W = (mat == 0) ? Wq : (mat == 1) ? Wk : Wv;
  Whi[idx] = (_Float16)W[r];
}

// ---------------- kernel A: fused QKV projection ----------------
// Block: 32 tokens, 4 waves. Wave w owns output-tiles j == w (mod 4), with its
// own double-buffered W LDS (8KB tile). NO barriers. Outputs fp16:
// Qh[tok][c], Kh[tok][c], Vt[c][tok] (transposed).
__global__ __launch_bounds__(256) void proj_kernel(
    const float* __restrict__ X,
    const float* __restrict__ bq, const float* __restrict__ bk, const float* __restrict__ bv,
    const _Float16* __restrict__ Whi,
    _Float16* __restrict__ Qh, _Float16* __restrict__ Kh, _Float16* __restrict__ Vt)
{
  __shared__ _Float16 wl[4][2][16 * 256];  // [wave][buf][col*feat] swizzled; 64 KB

  const int tid  = threadIdx.x;
  const int w    = tid >> 6;
  const int lane = tid & 63;
  const int l15  = lane & 15;
  const int lg   = lane >> 4;
  const int t0   = blockIdx.x * 32;

  // X A-fragments (2 x 16 tokens), cast fp16 (1-term).
  f16x8 xh[2][8];
  #pragma unroll
  for (int f = 0; f < 2; ++f) {
    const float* src = X + (size_t)(t0 + f * 16 + l15) * C + lg * 8;
    #pragma unroll
    for (int kk = 0; kk < 8; ++kk) {
      float4 a = *(const float4*)(src + kk * 32);
      float4 b = *(const float4*)(src + kk * 32 + 4);
      f16x8 h;
      h[0] = (_Float16)a.x; h[1] = (_Float16)a.y;
      h[2] = (_Float16)a.z; h[3] = (_Float16)a.w;
      h[4] = (_Float16)b.x; h[5] = (_Float16)b.y;
      h[6] = (_Float16)b.z; h[7] = (_Float16)b.w;
      xh[f][kk] = h;
    }
  }

  // Staging offsets: slot g = i*64+lane of 512; col=g>>5, p=g&31,
  // src chunk c=(p&24)|((p^col)&7).
  int soff[8];
  #pragma unroll
  for (int i = 0; i < 8; ++i) {
    int g = i * 64 + lane;
    int col = g >> 5, p = g & 31;
    int c = (p & 24) | ((p ^ col) & 7);
    soff[i] = col * 256 + c * 8;
  }
  // Compute-read swizzled offsets (bytes in [16][256] tile).
  int koff[8];
  {
    const int pm = l15 & 7;
    #pragma unroll
    for (int kk = 0; kk < 8; ++kk) {
      int cch = kk * 4 + lg;
      int p = (cch & 24) | ((cch ^ pm) & 7);
      koff[kk] = l15 * 512 + p * 16;
    }
  }

  auto stage = [&](int buf, int j) {
    const int rowbase = (j >> 4) * 256 + (j & 15) * 16;
    const _Float16* src0 = Whi + (size_t)rowbase * 256;
    char* dst = (char*)&wl[w][buf][0];
    #pragma unroll
    for (int i = 0; i < 8; ++i)
      gll16(src0 + soff[i], dst + i * 1024);
  };

  stage(0, w);
  stage(1, w + 4);

  #pragma unroll 1
  for (int i = 0; i < 12; ++i) {
    const int j = w + i * 4;
    // Sound while a younger 8-gll stage exists (i<=10); last iter must drain
    // (only ~2 stores are younger than tile 11's glls).
    if (i < 11) { VMCNT(8); } else { VMCNT(0); }
    const char* bb = (const char*)&wl[w][i & 1][0];
    f32x4 acc0 = {0.f, 0.f, 0.f, 0.f};
    f32x4 acc1 = {0.f, 0.f, 0.f, 0.f};
    #pragma unroll
    for (int kk = 0; kk < 8; ++kk) {
      f16x8 bh = *(const f16x8*)(bb + koff[kk]);
      acc0 = MFMA(xh[0][kk], bh, acc0);
      acc1 = MFMA(xh[1][kk], bh, acc1);
    }

    // stores FIRST (older than next stage in vmcnt queue)
    const int mat = j >> 4;
    const int cg  = (j & 15) * 16 + l15;
    const float bias = ((mat == 0) ? bq : (mat == 1) ? bk : bv)[cg];
    #pragma unroll
    for (int f = 0; f < 2; ++f) {
      f32x4 acc = f ? acc1 : acc0;
      const int tok0 = t0 + f * 16 + lg * 4;
      if (mat == 2) {
        f16x4 v4;
        #pragma unroll
        for (int r = 0; r < 4; ++r) v4[r] = (_Float16)(acc[r] + bias);
        *(f16x4*)(Vt + (size_t)cg * NTOK + tok0) = v4;
      } else {
        _Float16* P = (mat == 0) ? Qh : Kh;
        #pragma unroll
        for (int r = 0; r < 4; ++r)
          P[(size_t)(tok0 + r) * C + cg] = (_Float16)(acc[r] + bias);
      }
    }

    LGKMCNT0();                       // all ds_reads of buf consumed
    if (i < 10) stage(i & 1, w + (i + 2) * 4);
  }
}

// ---------------- kernel B: flash attention per segment ----------------
// Block = 32 Q-rows (2 waves x 16). K double-buffered in LDS (async gll);
// V(t+1) register-prefetched at end of iter t (issued AFTER stageK(t+1), so
// every wait in the loop is counted -- no vmcnt(0) anywhere). One barrier/iter.
__global__ __launch_bounds__(128, 2) void attn_kernel(
    const _Float16* __restrict__ Qh, const _Float16* __restrict__ Kh,
    const _Float16* __restrict__ Vt, float* __restrict__ Out)
{
  __shared__ _Float16 k_lds[2][32 * 256];  // chunk-XOR-swizzled; 32 KB
  __shared__ _Float16 p_lds[2][16][40];    // wave-private; 2.5 KB

  const int tid  = threadIdx.x;
  const int w    = tid >> 6;
  const int lane = tid & 63;
  const int l15  = lane & 15;
  const int lg   = lane >> 4;

  // XCD-bijective swizzle: 768 = 8 * 96
  const int bid = blockIdx.x;
  const int qrow0 = ((bid & 7) * 96 + (bid >> 3)) * 32;

  int seg = 0;
  #pragma unroll
  for (int i = 1; i < 8; ++i)
    if (qrow0 >= c_off[i]) seg = i;
  const int s0 = c_off[seg];
  const int nt = (c_off[seg + 1] - s0) >> 5;

  // Q fragments (B-operand: col=l15=qrow), fp16 direct.
  f16x8 qf[8];
  {
    const _Float16* src = Qh + (size_t)(qrow0 + w * 16 + l15) * C + lg * 8;
    #pragma unroll
    for (int kk = 0; kk < 8; ++kk) qf[kk] = *(const f16x8*)(src + kk * 32);
  }

  // K staging offsets: slot g = w*512 + i*64 + lane; row r=g>>5, p=g&31,
  // src chunk c=(p&24)|((p^r)&7).
  int kso[8];
  #pragma unroll
  for (int i = 0; i < 8; ++i) {
    int g = w * 512 + i * 64 + lane;
    int r = g >> 5, p = g & 31;
    int c = (p & 24) | ((p ^ r) & 7);
    kso[i] = r * 256 + c * 8;
  }
  // K read offsets (A-operand rows=keys), swizzled.
  int koff[8];
  {
    const int pm = l15 & 7;
    #pragma unroll
    for (int kk = 0; kk < 8; ++kk) {
      int cch = kk * 4 + lg;
      int p = (cch & 24) | ((cch ^ pm) & 7);
      koff[kk] = l15 * 512 + p * 16;  // row l15; row l15+16 is +8192
    }
  }

  // V loads: dim = db*16 + l15, tokens kv + lg*8 ..+7. Rows are 64B-line
  // aligned; the 4 lg-lanes of one l15 share one line -> coalesced.
  const _Float16* vbase = Vt + (size_t)l15 * NTOK + s0 + lg * 8;

  auto stageK = [&](int buf, int kv) {
    const _Float16* ks = Kh + (size_t)(s0 + kv) * C;
    char* kd = (char*)&k_lds[buf][0] + w * 8192;
    #pragma unroll
    for (int i = 0; i < 8; ++i) gll16(ks + kso[i], kd + i * 1024);
  };

  f16x8 vf[16];

  // prologue: K(0) staged, V(0) issued after it -> VMCNT(16) proves K(0)
  // landed while V(0) stays in flight.
  stageK(0, 0);
  #pragma unroll
  for (int db = 0; db < 16; ++db)
    vf[db] = *(const f16x8*)(vbase + (size_t)db * (16 * NTOK));
  VMCNT(16);
  BAR();

  f32x4 o[16];
  #pragma unroll
  for (int db = 0; db < 16; ++db) o[db] = (f32x4){0.f, 0.f, 0.f, 0.f};
  float m_ = -1e30f;   // running max for q-row l15 (replicated over lg)
  float ls = 0.f;

  #pragma unroll 1
  for (int t = 0; t < nt; ++t) {
    const int buf = t & 1;
    const int kvn = (t + 1 < nt) ? (t + 1) << 5 : 0;
    stageK(buf ^ 1, kvn);   // 8 glls, younger than V(t) -> PV waits stay counted

    // ---- S^T = K Q^T : 1-term fp16, fp32 acc ----
    const char* kb = (const char*)&k_lds[buf][0];
    f32x4 s0v = {0.f, 0.f, 0.f, 0.f};
    f32x4 s1v = {0.f, 0.f, 0.f, 0.f};
    #pragma unroll
    for (int kk = 0; kk < 8; ++kk) {
      f16x8 b0 = *(const f16x8*)(kb + koff[kk]);
      f16x8 b1 = *(const f16x8*)(kb + koff[kk] + 8192);
      s0v = MFMA(b0, qf[kk], s0v);
      s1v = MFMA(b1, qf[kk], s1v);
    }

    // ---- lane-local online softmax for q-row l15 ----
    float pmax = fmaxf(fmaxf(fmaxf(s0v[0], s0v[1]), fmaxf(s0v[2], s0v[3])),
                       fmaxf(fmaxf(s1v[0], s1v[1]), fmaxf(s1v[2], s1v[3])));
    pmax = fmaxf(pmax, __shfl_xor(pmax, 16));
    pmax = fmaxf(pmax, __shfl_xor(pmax, 32));

    const bool need = !__all(pmax <= m_ + 8.f);   // defer-rescale (T13)
    float scale = 1.f;
    if (need) {
      const float mn = fmaxf(m_, pmax);
      scale = __expf(m_ - mn);
      m_ = mn;
    }
    #pragma unroll
    for (int r = 0; r < 4; ++r) {
      s0v[r] = __expf(s0v[r] - m_);
      s1v[r] = __expf(s1v[r] - m_);
    }
    float rs = (s0v[0] + s0v[1]) + (s0v[2] + s0v[3]) +
               (s1v[0] + s1v[1]) + (s1v[2] + s1v[3]);
    rs += __shfl_xor(rs, 16);
    rs += __shfl_xor(rs, 32);
    ls = ls * scale + rs;

    // ---- P -> p_lds (wave-private; same-wave RAW via lgkmcnt) ----
    {
      f16x2 a = {(_Float16)s0v[0], (_Float16)s0v[1]};
      f16x2 b = {(_Float16)s0v[2], (_Float16)s0v[3]};
      f16x2 c = {(_Float16)s1v[0], (_Float16)s1v[1]};
      f16x2 d = {(_Float16)s1v[2], (_Float16)s1v[3]};
      *(f16x2*)&p_lds[w][l15][lg * 4]          = a;
      *(f16x2*)&p_lds[w][l15][lg * 4 + 2]      = b;
      *(f16x2*)&p_lds[w][l15][16 + lg * 4]     = c;
      *(f16x2*)&p_lds[w][l15][16 + lg * 4 + 2] = d;
    }

    // ---- rescale O (rows lg*4+r) only when max moved ----
    if (need) {
      float s4[4];
      #pragma unroll
      for (int r = 0; r < 4; ++r) s4[r] = __shfl(scale, lg * 4 + r);
      #pragma unroll
      for (int db = 0; db < 16; ++db) {
        #pragma unroll
        for (int r = 0; r < 4; ++r) o[db][r] *= s4[r];
      }
    }

    // ---- O += P V (vf = V(t), prefetched last iter; waits counted >=8) ----
    f16x8 pfrag = *(const f16x8*)&p_lds[w][l15][lg * 8];
    #pragma unroll
    for (int db = 0; db < 16; ++db)
      o[db] = MFMA(pfrag, vf[db], o[db]);

    // ---- prefetch V(t+1) into registers (younger than K(t+1) glls) ----
    {
      const _Float16* vp = vbase + kvn;
      #pragma unroll
      for (int db = 0; db < 16; ++db)
        vf[db] = *(const f16x8*)(vp + (size_t)db * (16 * NTOK));
    }

    // queue: [K(t+1) 8 glls, V(t+1) 16]; <=16 outstanding -> K(t+1) landed,
    // V(t+1) still in flight across the barrier.
    VMCNT(16);
    BAR();
  }

  // ---- epilogue: normalize and store fp32 ----
  float l4[4];
  #pragma unroll
  for (int r = 0; r < 4; ++r) l4[r] = 1.f / __shfl(ls, lg * 4 + r);
  const int orow = qrow0 + w * 16 + lg * 4;
  #pragma unroll
  for (int db = 0; db < 16; ++db) {
    #pragma unroll
    for (int r = 0; r < 4; ++r) {
      Out[(size_t)(orow + r) * C + db * 16 + l15] = o[db][r] * l4[r];
    }
  }
}

extern "C" void kernel_launch(void* const* d_in, const int* in_sizes, int n_in,
                              void* d_out, int out_size, void* d_ws, size_t ws_size,
                              hipStream_t stream)
{
  const float* X  = (const float*)d_in[0];
  // d_in[1] = indices (unused by the reference math)
  const float* Wq = (const float*)d_in[2];
  const float* bq = (const float*)d_in[3];
  const float* Wk = (const float*)d_in[4];
  const float* bk = (const float*)d_in[5];
  const float* Wv = (const float*)d_in[6];
  const float* bv = (const float*)d_in[7];
  float* Out = (float*)d_out;

  // workspace (all fp16): Qh | Kh | Vt (each NTOK*C) | Whi (3*65536)  ~38 MB
  const size_t SZ = (size_t)NTOK * C;
  _Float16* Qh  = (_Float16*)d_ws;
  _Float16* Kh  = Qh + SZ;
  _Float16* Vt  = Kh + SZ;
  _Float16* Whi = Vt + SZ;

  hipLaunchKernelGGL(wsplit_kernel, dim3(768), dim3(256), 0, stream,
                     Wq, Wk, Wv, Whi);
  hipLaunchKernelGGL(proj_kernel, dim3(768), dim3(256), 0, stream,
                     X, bq, bk, bv, Whi, Qh, Kh, Vt);
  hipLaunchKernelGGL(attn_kernel, dim3(768), dim3(128), 0, stream,
                     Qh, Kh, Vt, Out);
}